// Round 1
// 2032.821 us; speedup vs baseline: 1.5709x; 1.5709x over previous
//
#include <hip/hip_runtime.h>
#include <hip/hip_bf16.h>
#include <stdint.h>

typedef unsigned short u16;
typedef __attribute__((ext_vector_type(8))) short short8;
typedef __attribute__((ext_vector_type(4))) float f32x4;
typedef __attribute__((ext_vector_type(8))) unsigned short u16x8;

#define D_INK 2048
#define NLAT  32768
#define NTOK  4096
#define TOPK  32
#define CANDMAX 192

__device__ __forceinline__ u16 f2bf(float f) {
  __hip_bfloat16 h = __float2bfloat16(f);
  u16 u; __builtin_memcpy(&u, &h, 2); return u;
}

// async global->LDS, 16B per lane; LDS dest = wave-uniform base + lane*16
__device__ __forceinline__ void load_lds16(const u16* g, u16* l) {
  __builtin_amdgcn_global_load_lds(
      (const __attribute__((address_space(1))) unsigned int*)g,
      (__attribute__((address_space(3))) unsigned int*)l, 16, 0, 0);
}

// ---------------- convert kernels ----------------
__global__ __launch_bounds__(256) void convert_w_kernel(const float* __restrict__ in, u16* __restrict__ out) {
  size_t i = ((size_t)blockIdx.x * 256 + threadIdx.x) * 8;
  float4 a = *reinterpret_cast<const float4*>(in + i);
  float4 b = *reinterpret_cast<const float4*>(in + i + 4);
  u16x8 o;
  o[0]=f2bf(a.x); o[1]=f2bf(a.y); o[2]=f2bf(a.z); o[3]=f2bf(a.w);
  o[4]=f2bf(b.x); o[5]=f2bf(b.y); o[6]=f2bf(b.z); o[7]=f2bf(b.w);
  *reinterpret_cast<u16x8*>(out + i) = o;
}

__global__ __launch_bounds__(256) void convert_x_kernel(const float* __restrict__ x, const float* __restrict__ b_dec,
                                                        u16* __restrict__ out) {
  size_t i = ((size_t)blockIdx.x * 256 + threadIdx.x) * 8;
  int d = (int)(i & (D_INK - 1));
  float4 a = *reinterpret_cast<const float4*>(x + i);
  float4 b = *reinterpret_cast<const float4*>(x + i + 4);
  float4 ba = *reinterpret_cast<const float4*>(b_dec + d);
  float4 bb = *reinterpret_cast<const float4*>(b_dec + d + 4);
  u16x8 o;
  o[0]=f2bf(a.x-ba.x); o[1]=f2bf(a.y-ba.y); o[2]=f2bf(a.z-ba.z); o[3]=f2bf(a.w-ba.w);
  o[4]=f2bf(b.x-bb.x); o[5]=f2bf(b.y-bb.y); o[6]=f2bf(b.z-bb.z); o[7]=f2bf(b.w-bb.w);
  *reinterpret_cast<u16x8*>(out + i) = o;
}

// ---------------- bf16 MFMA GEMM: pre[t][l] = (x-b_dec)·W_enc[l] + b_enc[l] ----------------
// 128x128 tile, BK=64, 4 waves (2x2 of 64x64), 16x16x32 MFMA.
// LDS tiles stored as 16B chunks with XOR swizzle: chunk(r,c) at r*8 + (c ^ (r&7)).
__global__ __launch_bounds__(256) void gemm_kernel(
    const u16* __restrict__ A,   // Xhi [NTOK][2048] bf16
    const u16* __restrict__ B,   // Whi [NLAT][2048] bf16
    const float* __restrict__ b_enc,
    u16* __restrict__ pre,       // [Tc][NLAT] bf16 (chunk-local rows)
    int tokBase, int tokTiles)
{
  __shared__ alignas(16) u16 As[128 * 64];
  __shared__ alignas(16) u16 Bs[128 * 64];
  const int tokTile = blockIdx.x % tokTiles;   // token-tile fastest -> 32 blocks share one W-tile in L2
  const int latTile = blockIdx.x / tokTiles;
  const int tid  = threadIdx.x;
  const int wave = tid >> 6, lane = tid & 63;
  const int wm = wave >> 1, wn = wave & 1;
  const int rloc = lane >> 3, cswz = lane & 7;
  const int cdat = cswz ^ rloc;                // global k-chunk this lane fetches
  const int m16 = lane & 15, quad = lane >> 4;

  const int rowA0 = tokBase + tokTile * 128;
  const int rowB0 = latTile * 128;

  f32x4 acc[4][4];
  #pragma unroll
  for (int i = 0; i < 4; ++i)
    #pragma unroll
    for (int j = 0; j < 4; ++j) { acc[i][j][0]=0.f; acc[i][j][1]=0.f; acc[i][j][2]=0.f; acc[i][j][3]=0.f; }

  for (int kt = 0; kt < D_INK / 64; ++kt) {
    const int k0 = kt * 64;
    #pragma unroll
    for (int i = 0; i < 4; ++i) {
      const int seg = wave * 4 + i;            // 16 segments of 8 rows
      const u16* ga = A + (size_t)(rowA0 + seg * 8 + rloc) * D_INK + k0 + cdat * 8;
      load_lds16(ga, &As[seg * 64 * 8]);
      const u16* gb = B + (size_t)(rowB0 + seg * 8 + rloc) * D_INK + k0 + cdat * 8;
      load_lds16(gb, &Bs[seg * 64 * 8]);
    }
    __syncthreads();                           // compiler drains vmcnt before s_barrier
    #pragma unroll
    for (int ks = 0; ks < 2; ++ks) {
      short8 af[4], bf[4];
      #pragma unroll
      for (int mi = 0; mi < 4; ++mi) {
        const int r = wm * 64 + mi * 16 + m16;
        const int ci = r * 8 + ((ks * 4 + quad) ^ (r & 7));
        af[mi] = *reinterpret_cast<const short8*>(&As[ci * 8]);
      }
      #pragma unroll
      for (int ni = 0; ni < 4; ++ni) {
        const int r = wn * 64 + ni * 16 + m16;
        const int ci = r * 8 + ((ks * 4 + quad) ^ (r & 7));
        bf[ni] = *reinterpret_cast<const short8*>(&Bs[ci * 8]);
      }
      #pragma unroll
      for (int mi = 0; mi < 4; ++mi)
        #pragma unroll
        for (int ni = 0; ni < 4; ++ni)
          acc[mi][ni] = __builtin_amdgcn_mfma_f32_16x16x32_bf16(af[mi], bf[ni], acc[mi][ni], 0, 0, 0);
    }
    __syncthreads();
  }

  // epilogue: D layout col=lane&15 (latent), row=quad*4+reg (token). +b_enc, store bf16.
  #pragma unroll
  for (int ni = 0; ni < 4; ++ni) {
    const int col = latTile * 128 + wn * 64 + ni * 16 + m16;
    const float be = b_enc[col];
    #pragma unroll
    for (int mi = 0; mi < 4; ++mi) {
      const int row = tokTile * 128 + wm * 64 + mi * 16 + quad * 4;  // chunk-local token row
      #pragma unroll
      for (int r = 0; r < 4; ++r)
        pre[(size_t)(row + r) * NLAT + col] = f2bf(acc[mi][ni][r] + be);
    }
  }
}

// ---------------- per-token: histogram-threshold candidates -> fp64 rescore -> top-32 -> decode ----------------
// LDS cut 27.6KB -> ~14.1KB (hist only covers values >= 2.0: keys 0xC000..0xFFFF, 1024 bins)
// -> 8 blocks/CU (wave-capped). __launch_bounds__(256,8) pins VGPR<=64 so regs don't become the limiter.
__global__ __launch_bounds__(256, 8) void topk_decode_kernel(
    const u16* __restrict__ pre, const float* __restrict__ x,
    const float* __restrict__ W_enc, const float* __restrict__ b_enc,
    const float* __restrict__ W_dec, const float* __restrict__ b_dec,
    float* __restrict__ out, int tokBase)
{
  __shared__ int   hist[1024];                 // bins 3072..4095 (values >= 2.0)
  __shared__ alignas(16) float xs[D_INK];
  __shared__ int   candIdx[CANDMAX];
  __shared__ float candVal[CANDMAX];
  __shared__ int   candCount;
  __shared__ int   tauBin;
  __shared__ float selVal[TOPK];
  __shared__ int   selIdx[TOPK];

  const int tid = threadIdx.x;
  const int lane = tid & 63, wave = tid >> 6;
  const int t = tokBase + blockIdx.x;

  for (int i = tid; i < 1024; i += 256) hist[i] = 0;
  if (tid == 0) candCount = 0;
  for (int i = tid; i < D_INK; i += 256) xs[i] = x[(size_t)t * D_INK + i] - b_dec[i];
  __syncthreads();

  const uint4* prow = reinterpret_cast<const uint4*>(pre + (size_t)blockIdx.x * NLAT);
  // pass 1: histogram of sortable bf16 keys, values >= 2.0 only.
  // 64th-largest of 32768 ~N(0,1) values sits near 2.9; ~745 values/token exceed 2.0 (floor unreachable).
  for (int it = 0; it < NLAT / (256 * 8); ++it) {
    uint4 v = prow[it * 256 + tid];
    unsigned w[4] = {v.x, v.y, v.z, v.w};
    #pragma unroll
    for (int j = 0; j < 4; ++j) {
      unsigned lo = w[j] & 0xFFFFu, hi = w[j] >> 16;
      unsigned klo = (lo & 0x8000u) ? (0xFFFFu ^ lo) : (lo | 0x8000u);
      unsigned khi = (hi & 0x8000u) ? (0xFFFFu ^ hi) : (hi | 0x8000u);
      if (klo >= 0xC000u) atomicAdd(&hist[(klo >> 4) - 3072], 1);
      if (khi >= 0xC000u) atomicAdd(&hist[(khi >> 4) - 3072], 1);
    }
  }
  __syncthreads();
  // wave-parallel threshold scan: 64 groups of 16 bins, suffix-prefix + ballot.
  if (wave == 0) {
    const int g = 63 - lane;                   // lane 0 -> topmost group
    int c = 0;
    #pragma unroll
    for (int j = 0; j < 16; ++j) c += hist[g * 16 + j];
    int p = c;                                 // inclusive prefix from top
    #pragma unroll
    for (int off = 1; off < 64; off <<= 1) {
      int v = __shfl_up(p, off);
      if (lane >= off) p += v;
    }
    unsigned long long m = __ballot(p >= 64);
    int tb;
    if (m == 0ull) {
      tb = 3072;                               // floor = bin of 2.0 (statistically unreachable)
    } else {
      const int fl = __ffsll((unsigned long long)m) - 1;
      const int cumAbove = __shfl(p - c, fl);  // cum of groups above the boundary group
      const int gb = 63 - fl;
      int h = (lane < 16) ? hist[gb * 16 + 15 - lane] : 0;
      int q = h;
      #pragma unroll
      for (int off = 1; off < 16; off <<= 1) {
        int v = __shfl_up(q, off);
        if (lane >= off) q += v;
      }
      unsigned long long m2 = __ballot(lane < 16 && (cumAbove + q) >= 64);
      const int fl2 = __ffsll((unsigned long long)m2) - 1;
      tb = 3072 + gb * 16 + 15 - fl2;
    }
    if (lane == 0) tauBin = tb;
  }
  __syncthreads();
  const int tb = tauBin;
  // pass 2: collect candidate indices (L2-hot re-read)
  for (int it = 0; it < NLAT / (256 * 8); ++it) {
    uint4 v = prow[it * 256 + tid];
    const int base = (it * 256 + tid) * 8;
    unsigned w[4] = {v.x, v.y, v.z, v.w};
    #pragma unroll
    for (int j = 0; j < 4; ++j) {
      unsigned lo = w[j] & 0xFFFFu, hi = w[j] >> 16;
      unsigned klo = (lo & 0x8000u) ? (0xFFFFu ^ lo) : (lo | 0x8000u);
      unsigned khi = (hi & 0x8000u) ? (0xFFFFu ^ hi) : (hi | 0x8000u);
      if ((int)(klo >> 4) >= tb) { int p = atomicAdd(&candCount, 1); if (p < CANDMAX) candIdx[p] = base + 2 * j; }
      if ((int)(khi >> 4) >= tb) { int p = atomicAdd(&candCount, 1); if (p < CANDMAX) candIdx[p] = base + 2 * j + 1; }
    }
  }
  __syncthreads();
  const int C = min(candCount, CANDMAX);
  // fp64 rescore: exact-class ranking values. float2 loads, dual accumulators.
  for (int c = wave; c < C; c += 4) {
    const int li = candIdx[c];
    const float2* wr = reinterpret_cast<const float2*>(W_enc + (size_t)li * D_INK);
    const float2* xp = reinterpret_cast<const float2*>(xs);
    double s0 = 0.0, s1 = 0.0;
    #pragma unroll 8
    for (int i = 0; i < D_INK / 128; ++i) {
      const int p = lane + i * 64;
      const float2 w2 = wr[p];
      const float2 x2 = xp[p];
      s0 += (double)x2.x * (double)w2.x;
      s1 += (double)x2.y * (double)w2.y;
    }
    double s = s0 + s1;
    for (int off = 32; off > 0; off >>= 1) s += __shfl_down(s, off);
    if (lane == 0) candVal[c] = (float)(s + (double)b_enc[li]);
  }
  __syncthreads();
  // wave-0 top-32 selection (val desc, latent idx asc on ties)
  if (wave == 0) {
    float v0[3]; int s0[3]; int ix[3];
    #pragma unroll
    for (int j = 0; j < 3; ++j) {
      const int c = lane + j * 64;
      if (c < C) { v0[j] = candVal[c]; s0[j] = c; ix[j] = candIdx[c]; }
      else       { v0[j] = -1e30f;     s0[j] = -1; ix[j] = 0x7FFFFFFF; }
    }
    for (int r = 0; r < TOPK; ++r) {
      float bv = v0[0]; int bi = ix[0], bs = s0[0];
      #pragma unroll
      for (int j = 1; j < 3; ++j)
        if (v0[j] > bv || (v0[j] == bv && ix[j] < bi)) { bv = v0[j]; bi = ix[j]; bs = s0[j]; }
      for (int off = 32; off > 0; off >>= 1) {
        float ov = __shfl_down(bv, off); int oi = __shfl_down(bi, off); int os = __shfl_down(bs, off);
        if (ov > bv || (ov == bv && oi < bi)) { bv = ov; bi = oi; bs = os; }
      }
      bv = __shfl(bv, 0); bi = __shfl(bi, 0); bs = __shfl(bs, 0);
      if (lane == 0) {
        if (bv <= -1e29f) { selVal[r] = 0.0f; selIdx[r] = 0; }
        else              { selVal[r] = bv;   selIdx[r] = bi; }
      }
      #pragma unroll
      for (int j = 0; j < 3; ++j) if (s0[j] == bs) v0[j] = -1e30f;
    }
  }
  __syncthreads();
  // decode: x_hat = b_dec + sum_k act_k * W_dec[idx_k]  (float4 vectorized, k-order preserved)
  for (int d0 = tid * 4; d0 < D_INK; d0 += 1024) {
    float4 acc = *reinterpret_cast<const float4*>(b_dec + d0);
    #pragma unroll 8
    for (int k = 0; k < TOPK; ++k) {
      const float a = selVal[k];
      const float4 w = *reinterpret_cast<const float4*>(W_dec + (size_t)selIdx[k] * D_INK + d0);
      acc.x += a * w.x; acc.y += a * w.y; acc.z += a * w.z; acc.w += a * w.w;
    }
    *reinterpret_cast<float4*>(out + (size_t)t * D_INK + d0) = acc;
  }
}

// ---------------- host ----------------
extern "C" void kernel_launch(void* const* d_in, const int* in_sizes, int n_in,
                              void* d_out, int out_size, void* d_ws, size_t ws_size,
                              hipStream_t stream) {
  const float* x     = (const float*)d_in[0];
  const float* W_enc = (const float*)d_in[1];
  const float* b_enc = (const float*)d_in[2];
  const float* W_dec = (const float*)d_in[3];
  const float* b_dec = (const float*)d_in[4];
  float* out = (float*)d_out;

  const size_t WHI_BYTES = (size_t)NLAT * D_INK * 2;  // 128 MiB
  const size_t XHI_BYTES = (size_t)NTOK * D_INK * 2;  //  16 MiB
  u16* Whi = (u16*)d_ws;
  u16* Xhi = (u16*)((char*)d_ws + WHI_BYTES);
  u16* pre = (u16*)((char*)d_ws + WHI_BYTES + XHI_BYTES);

  // token-chunk the pre buffer to fit ws
  size_t preAvail = ws_size > (WHI_BYTES + XHI_BYTES) ? ws_size - WHI_BYTES - XHI_BYTES : 0;
  int Tc = (int)(preAvail / ((size_t)NLAT * 2));
  if (Tc > NTOK) Tc = NTOK;
  Tc = (Tc / 128) * 128;
  if (Tc < 128) Tc = 128;

  convert_w_kernel<<<(NLAT * D_INK / 8) / 256, 256, 0, stream>>>(W_enc, Whi);
  convert_x_kernel<<<(NTOK * D_INK / 8) / 256, 256, 0, stream>>>(x, b_dec, Xhi);

  for (int tokBase = 0; tokBase < NTOK; tokBase += Tc) {
    const int ct = (NTOK - tokBase) < Tc ? (NTOK - tokBase) : Tc;
    const int tokTiles = ct / 128;
    gemm_kernel<<<tokTiles * (NLAT / 128), 256, 0, stream>>>(Xhi, Whi, b_enc, pre, tokBase, tokTiles);
    topk_decode_kernel<<<ct, 256, 0, stream>>>(pre, x, W_enc, b_enc, W_dec, b_dec, out, tokBase);
  }
}

// Round 2
// 1814.769 us; speedup vs baseline: 1.7596x; 1.1202x over previous
//
#include <hip/hip_runtime.h>
#include <hip/hip_bf16.h>
#include <stdint.h>

typedef unsigned short u16;
typedef __attribute__((ext_vector_type(8))) short short8;
typedef __attribute__((ext_vector_type(4))) float f32x4;
typedef __attribute__((ext_vector_type(8))) unsigned short u16x8;

#define D_INK 2048
#define NLAT  32768
#define NTOK  4096
#define TOPK  32
#define CANDMAX 192

__device__ __forceinline__ u16 f2bf(float f) {
  __hip_bfloat16 h = __float2bfloat16(f);
  u16 u; __builtin_memcpy(&u, &h, 2); return u;
}

// async global->LDS, 16B per lane; LDS dest = wave-uniform base + lane*16
__device__ __forceinline__ void load_lds16(const u16* g, u16* l) {
  __builtin_amdgcn_global_load_lds(
      (const __attribute__((address_space(1))) unsigned int*)g,
      (__attribute__((address_space(3))) unsigned int*)l, 16, 0, 0);
}

// ---------------- convert kernels ----------------
__global__ __launch_bounds__(256) void convert_w_kernel(const float* __restrict__ in, u16* __restrict__ out) {
  size_t i = ((size_t)blockIdx.x * 256 + threadIdx.x) * 8;
  float4 a = *reinterpret_cast<const float4*>(in + i);
  float4 b = *reinterpret_cast<const float4*>(in + i + 4);
  u16x8 o;
  o[0]=f2bf(a.x); o[1]=f2bf(a.y); o[2]=f2bf(a.z); o[3]=f2bf(a.w);
  o[4]=f2bf(b.x); o[5]=f2bf(b.y); o[6]=f2bf(b.z); o[7]=f2bf(b.w);
  *reinterpret_cast<u16x8*>(out + i) = o;
}

__global__ __launch_bounds__(256) void convert_x_kernel(const float* __restrict__ x, const float* __restrict__ b_dec,
                                                        u16* __restrict__ out) {
  size_t i = ((size_t)blockIdx.x * 256 + threadIdx.x) * 8;
  int d = (int)(i & (D_INK - 1));
  float4 a = *reinterpret_cast<const float4*>(x + i);
  float4 b = *reinterpret_cast<const float4*>(x + i + 4);
  float4 ba = *reinterpret_cast<const float4*>(b_dec + d);
  float4 bb = *reinterpret_cast<const float4*>(b_dec + d + 4);
  u16x8 o;
  o[0]=f2bf(a.x-ba.x); o[1]=f2bf(a.y-ba.y); o[2]=f2bf(a.z-ba.z); o[3]=f2bf(a.w-ba.w);
  o[4]=f2bf(b.x-bb.x); o[5]=f2bf(b.y-bb.y); o[6]=f2bf(b.z-bb.z); o[7]=f2bf(b.w-bb.w);
  *reinterpret_cast<u16x8*>(out + i) = o;
}

// ---------------- bf16 MFMA GEMM, 256x256 tile, BK=64, 8 waves (2Mx4N) ----------------
// Double-buffered LDS (128 KiB), counted-vmcnt prefetch (T3/T4): next K-tile's
// 8 global_load_lds per wave stay in flight across the current tile's compute.
// LDS tiles stored as 16B chunks with XOR swizzle: chunk(r,c) at r*8 + (c ^ (r&7)).
// Epilogue: acc+bias -> LDS transpose -> fully coalesced 16B stores (kills 2x write amp).
__global__ __launch_bounds__(512, 2) void gemm_kernel(
    const u16* __restrict__ A,   // Xhi [NTOK][2048] bf16
    const u16* __restrict__ B,   // Whi [NLAT][2048] bf16
    const float* __restrict__ b_enc,
    u16* __restrict__ pre,       // [Tc][NLAT] bf16 (chunk-local rows)
    int tokBase, int tokTiles)
{
  __shared__ alignas(16) u16 sh[65536];        // [buf:2][A 16384 | B 16384] == T[256*256]
  const int tid  = threadIdx.x;
  const int wave = tid >> 6, lane = tid & 63;
  const int wm = wave >> 2, wn = wave & 3;     // 2 x 4 wave grid -> per-wave 128x64 output
  const int rloc = lane >> 3, cswz = lane & 7;
  const int cdat = cswz ^ rloc;                // global k-chunk this lane fetches (pre-swizzled source)
  const int m16 = lane & 15, quad = lane >> 4;

  // XCD-aware bijective swizzle: 16 token-blocks sharing a W-tile land on one XCD's L2.
  int bid = blockIdx.x;
  const int nwg = tokTiles * (NLAT / 256);
  if ((nwg & 7) == 0) { const int cpx = nwg >> 3; bid = (bid & 7) * cpx + (bid >> 3); }
  const int tokTile = bid % tokTiles;          // token-tile fastest
  const int latTile = bid / tokTiles;

  const int rowA0 = tokBase + tokTile * 256;
  const int rowB0 = latTile * 256;

  f32x4 acc[8][4];
  #pragma unroll
  for (int i = 0; i < 8; ++i)
    #pragma unroll
    for (int j = 0; j < 4; ++j) { acc[i][j][0]=0.f; acc[i][j][1]=0.f; acc[i][j][2]=0.f; acc[i][j][3]=0.f; }

  // 8 global_load_lds per wave per STAGE (4 A + 4 B) -> vmcnt(8) is exact.
  #define STAGE(kt_) do {                                                          \
    const int buf_ = ((kt_) & 1) << 15;                                            \
    const int k0_  = (kt_) << 6;                                                   \
    _Pragma("unroll")                                                              \
    for (int i_ = 0; i_ < 4; ++i_) {                                               \
      const int seg_ = wave * 4 + i_;                                              \
      load_lds16(A + (size_t)(rowA0 + seg_ * 8 + rloc) * D_INK + k0_ + cdat * 8,   \
                 &sh[buf_ + seg_ * 512]);                                          \
      load_lds16(B + (size_t)(rowB0 + seg_ * 8 + rloc) * D_INK + k0_ + cdat * 8,   \
                 &sh[buf_ + 16384 + seg_ * 512]);                                  \
    }                                                                              \
  } while (0)

  #define COMPUTE(kt_) do {                                                        \
    const int buf_ = ((kt_) & 1) << 15;                                            \
    _Pragma("unroll")                                                              \
    for (int ks_ = 0; ks_ < 2; ++ks_) {                                            \
      short8 af_[8], bf_[4];                                                       \
      _Pragma("unroll")                                                            \
      for (int mi_ = 0; mi_ < 8; ++mi_) {                                          \
        const int r_ = wm * 128 + mi_ * 16 + m16;                                  \
        const int ci_ = r_ * 8 + ((ks_ * 4 + quad) ^ (r_ & 7));                    \
        af_[mi_] = *reinterpret_cast<const short8*>(&sh[buf_ + ci_ * 8]);          \
      }                                                                            \
      _Pragma("unroll")                                                            \
      for (int ni_ = 0; ni_ < 4; ++ni_) {                                          \
        const int r_ = wn * 64 + ni_ * 16 + m16;                                   \
        const int ci_ = r_ * 8 + ((ks_ * 4 + quad) ^ (r_ & 7));                    \
        bf_[ni_] = *reinterpret_cast<const short8*>(&sh[buf_ + 16384 + ci_ * 8]);  \
      }                                                                            \
      __builtin_amdgcn_s_setprio(1);                                               \
      _Pragma("unroll")                                                            \
      for (int mi_ = 0; mi_ < 8; ++mi_)                                            \
        _Pragma("unroll")                                                          \
        for (int ni_ = 0; ni_ < 4; ++ni_)                                          \
          acc[mi_][ni_] = __builtin_amdgcn_mfma_f32_16x16x32_bf16(                 \
              af_[mi_], bf_[ni_], acc[mi_][ni_], 0, 0, 0);                         \
      __builtin_amdgcn_s_setprio(0);                                               \
    }                                                                              \
  } while (0)

  STAGE(0);
  for (int kt = 0; kt < D_INK / 64 - 1; ++kt) {
    STAGE(kt + 1);                              // prefetch next K-tile into the other buffer
    asm volatile("s_waitcnt vmcnt(8)" ::: "memory");   // this wave's current-tile loads done
    __builtin_amdgcn_s_barrier();               // -> ALL waves' current-tile loads done
    asm volatile("" ::: "memory");
    COMPUTE(kt);
    asm volatile("" ::: "memory");
    __builtin_amdgcn_s_barrier();               // all reads of buf done before next STAGE overwrites
  }
  asm volatile("s_waitcnt vmcnt(0)" ::: "memory");
  __builtin_amdgcn_s_barrier();
  asm volatile("" ::: "memory");
  COMPUTE(D_INK / 64 - 1);
  __syncthreads();                              // tiles dead; LDS reused as 256x256 u16 T

  // epilogue: bias add, stage to LDS, fully-coalesced 16B stores
  float be[4];
  #pragma unroll
  for (int ni = 0; ni < 4; ++ni) be[ni] = b_enc[latTile * 256 + wn * 64 + ni * 16 + m16];
  #pragma unroll
  for (int mi = 0; mi < 8; ++mi)
    #pragma unroll
    for (int ni = 0; ni < 4; ++ni)
      #pragma unroll
      for (int r = 0; r < 4; ++r) {
        const int row = wm * 128 + mi * 16 + quad * 4 + r;
        const int col = wn * 64 + ni * 16 + m16;
        sh[row * 256 + col] = f2bf(acc[mi][ni][r] + be[ni]);
      }
  __syncthreads();
  #pragma unroll
  for (int i = 0; i < 16; ++i) {
    const int idx = i * 512 + tid;               // 16B chunk id; row = idx>>5, chunk = idx&31
    const int row = idx >> 5, c = idx & 31;
    *reinterpret_cast<u16x8*>(pre + (size_t)(tokTile * 256 + row) * NLAT + latTile * 256 + c * 8)
        = *reinterpret_cast<const u16x8*>(&sh[idx * 8]);
  }
  #undef STAGE
  #undef COMPUTE
}

// ---------------- per-token: histogram-threshold candidates -> fp64 rescore -> top-32 -> decode ----------------
__global__ __launch_bounds__(256, 8) void topk_decode_kernel(
    const u16* __restrict__ pre, const float* __restrict__ x,
    const float* __restrict__ W_enc, const float* __restrict__ b_enc,
    const float* __restrict__ W_dec, const float* __restrict__ b_dec,
    float* __restrict__ out, int tokBase)
{
  __shared__ int   hist[1024];                 // bins 3072..4095 (values >= 2.0)
  __shared__ alignas(16) float xs[D_INK];
  __shared__ int   candIdx[CANDMAX];
  __shared__ float candVal[CANDMAX];
  __shared__ int   candCount;
  __shared__ int   tauBin;
  __shared__ float selVal[TOPK];
  __shared__ int   selIdx[TOPK];

  const int tid = threadIdx.x;
  const int lane = tid & 63, wave = tid >> 6;
  const int t = tokBase + blockIdx.x;

  for (int i = tid; i < 1024; i += 256) hist[i] = 0;
  if (tid == 0) candCount = 0;
  for (int i = tid; i < D_INK; i += 256) xs[i] = x[(size_t)t * D_INK + i] - b_dec[i];
  __syncthreads();

  const uint4* prow = reinterpret_cast<const uint4*>(pre + (size_t)blockIdx.x * NLAT);
  // pass 1: histogram of sortable bf16 keys, values >= 2.0 only.
  for (int it = 0; it < NLAT / (256 * 8); ++it) {
    uint4 v = prow[it * 256 + tid];
    unsigned w[4] = {v.x, v.y, v.z, v.w};
    #pragma unroll
    for (int j = 0; j < 4; ++j) {
      unsigned lo = w[j] & 0xFFFFu, hi = w[j] >> 16;
      unsigned klo = (lo & 0x8000u) ? (0xFFFFu ^ lo) : (lo | 0x8000u);
      unsigned khi = (hi & 0x8000u) ? (0xFFFFu ^ hi) : (hi | 0x8000u);
      if (klo >= 0xC000u) atomicAdd(&hist[(klo >> 4) - 3072], 1);
      if (khi >= 0xC000u) atomicAdd(&hist[(khi >> 4) - 3072], 1);
    }
  }
  __syncthreads();
  // wave-parallel threshold scan: 64 groups of 16 bins, suffix-prefix + ballot.
  if (wave == 0) {
    const int g = 63 - lane;                   // lane 0 -> topmost group
    int c = 0;
    #pragma unroll
    for (int j = 0; j < 16; ++j) c += hist[g * 16 + j];
    int p = c;                                 // inclusive prefix from top
    #pragma unroll
    for (int off = 1; off < 64; off <<= 1) {
      int v = __shfl_up(p, off);
      if (lane >= off) p += v;
    }
    unsigned long long m = __ballot(p >= 64);
    int tb;
    if (m == 0ull) {
      tb = 3072;                               // floor = bin of 2.0 (statistically unreachable)
    } else {
      const int fl = __ffsll((unsigned long long)m) - 1;
      const int cumAbove = __shfl(p - c, fl);  // cum of groups above the boundary group
      const int gb = 63 - fl;
      int h = (lane < 16) ? hist[gb * 16 + 15 - lane] : 0;
      int q = h;
      #pragma unroll
      for (int off = 1; off < 16; off <<= 1) {
        int v = __shfl_up(q, off);
        if (lane >= off) q += v;
      }
      unsigned long long m2 = __ballot(lane < 16 && (cumAbove + q) >= 64);
      const int fl2 = __ffsll((unsigned long long)m2) - 1;
      tb = 3072 + gb * 16 + 15 - fl2;
    }
    if (lane == 0) tauBin = tb;
  }
  __syncthreads();
  const int tb = tauBin;
  // pass 2: collect candidate indices (L2-hot re-read)
  for (int it = 0; it < NLAT / (256 * 8); ++it) {
    uint4 v = prow[it * 256 + tid];
    const int base = (it * 256 + tid) * 8;
    unsigned w[4] = {v.x, v.y, v.z, v.w};
    #pragma unroll
    for (int j = 0; j < 4; ++j) {
      unsigned lo = w[j] & 0xFFFFu, hi = w[j] >> 16;
      unsigned klo = (lo & 0x8000u) ? (0xFFFFu ^ lo) : (lo | 0x8000u);
      unsigned khi = (hi & 0x8000u) ? (0xFFFFu ^ hi) : (hi | 0x8000u);
      if ((int)(klo >> 4) >= tb) { int p = atomicAdd(&candCount, 1); if (p < CANDMAX) candIdx[p] = base + 2 * j; }
      if ((int)(khi >> 4) >= tb) { int p = atomicAdd(&candCount, 1); if (p < CANDMAX) candIdx[p] = base + 2 * j + 1; }
    }
  }
  __syncthreads();
  const int C = min(candCount, CANDMAX);
  // fp64 rescore: exact-class ranking values. float2 loads, dual accumulators.
  for (int c = wave; c < C; c += 4) {
    const int li = candIdx[c];
    const float2* wr = reinterpret_cast<const float2*>(W_enc + (size_t)li * D_INK);
    const float2* xp = reinterpret_cast<const float2*>(xs);
    double s0 = 0.0, s1 = 0.0;
    #pragma unroll 8
    for (int i = 0; i < D_INK / 128; ++i) {
      const int p = lane + i * 64;
      const float2 w2 = wr[p];
      const float2 x2 = xp[p];
      s0 += (double)x2.x * (double)w2.x;
      s1 += (double)x2.y * (double)w2.y;
    }
    double s = s0 + s1;
    for (int off = 32; off > 0; off >>= 1) s += __shfl_down(s, off);
    if (lane == 0) candVal[c] = (float)(s + (double)b_enc[li]);
  }
  __syncthreads();
  // wave-0 top-32 selection (val desc, latent idx asc on ties)
  if (wave == 0) {
    float v0[3]; int s0[3]; int ix[3];
    #pragma unroll
    for (int j = 0; j < 3; ++j) {
      const int c = lane + j * 64;
      if (c < C) { v0[j] = candVal[c]; s0[j] = c; ix[j] = candIdx[c]; }
      else       { v0[j] = -1e30f;     s0[j] = -1; ix[j] = 0x7FFFFFFF; }
    }
    for (int r = 0; r < TOPK; ++r) {
      float bv = v0[0]; int bi = ix[0], bs = s0[0];
      #pragma unroll
      for (int j = 1; j < 3; ++j)
        if (v0[j] > bv || (v0[j] == bv && ix[j] < bi)) { bv = v0[j]; bi = ix[j]; bs = s0[j]; }
      for (int off = 32; off > 0; off >>= 1) {
        float ov = __shfl_down(bv, off); int oi = __shfl_down(bi, off); int os = __shfl_down(bs, off);
        if (ov > bv || (ov == bv && oi < bi)) { bv = ov; bi = oi; bs = os; }
      }
      bv = __shfl(bv, 0); bi = __shfl(bi, 0); bs = __shfl(bs, 0);
      if (lane == 0) {
        if (bv <= -1e29f) { selVal[r] = 0.0f; selIdx[r] = 0; }
        else              { selVal[r] = bv;   selIdx[r] = bi; }
      }
      #pragma unroll
      for (int j = 0; j < 3; ++j) if (s0[j] == bs) v0[j] = -1e30f;
    }
  }
  __syncthreads();
  // decode: x_hat = b_dec + sum_k act_k * W_dec[idx_k]  (float4 vectorized, k-order preserved)
  for (int d0 = tid * 4; d0 < D_INK; d0 += 1024) {
    float4 acc = *reinterpret_cast<const float4*>(b_dec + d0);
    #pragma unroll 8
    for (int k = 0; k < TOPK; ++k) {
      const float a = selVal[k];
      const float4 w = *reinterpret_cast<const float4*>(W_dec + (size_t)selIdx[k] * D_INK + d0);
      acc.x += a * w.x; acc.y += a * w.y; acc.z += a * w.z; acc.w += a * w.w;
    }
    *reinterpret_cast<float4*>(out + (size_t)t * D_INK + d0) = acc;
  }
}

// ---------------- host ----------------
extern "C" void kernel_launch(void* const* d_in, const int* in_sizes, int n_in,
                              void* d_out, int out_size, void* d_ws, size_t ws_size,
                              hipStream_t stream) {
  const float* x     = (const float*)d_in[0];
  const float* W_enc = (const float*)d_in[1];
  const float* b_enc = (const float*)d_in[2];
  const float* W_dec = (const float*)d_in[3];
  const float* b_dec = (const float*)d_in[4];
  float* out = (float*)d_out;

  const size_t WHI_BYTES = (size_t)NLAT * D_INK * 2;  // 128 MiB
  const size_t XHI_BYTES = (size_t)NTOK * D_INK * 2;  //  16 MiB
  u16* Whi = (u16*)d_ws;
  u16* Xhi = (u16*)((char*)d_ws + WHI_BYTES);
  u16* pre = (u16*)((char*)d_ws + WHI_BYTES + XHI_BYTES);

  // token-chunk the pre buffer to fit ws (256-row granularity for the 256^2 gemm)
  size_t preAvail = ws_size > (WHI_BYTES + XHI_BYTES) ? ws_size - WHI_BYTES - XHI_BYTES : 0;
  int Tc = (int)(preAvail / ((size_t)NLAT * 2));
  if (Tc > NTOK) Tc = NTOK;
  Tc = (Tc / 256) * 256;
  if (Tc < 256) Tc = 256;

  convert_w_kernel<<<(NLAT * D_INK / 8) / 256, 256, 0, stream>>>(W_enc, Whi);
  convert_x_kernel<<<(NTOK * D_INK / 8) / 256, 256, 0, stream>>>(x, b_dec, Xhi);

  for (int tokBase = 0; tokBase < NTOK; tokBase += Tc) {
    const int ct = (NTOK - tokBase) < Tc ? (NTOK - tokBase) : Tc;
    const int tokTiles = ct / 256;
    gemm_kernel<<<tokTiles * (NLAT / 256), 512, 0, stream>>>(Xhi, Whi, b_enc, pre, tokBase, tokTiles);
    topk_decode_kernel<<<ct, 256, 0, stream>>>(pre, x, W_enc, b_enc, W_dec, b_dec, out, tokBase);
  }
}